// Round 1
// baseline (575.682 us; speedup 1.0000x reference)
//
#include <hip/hip_runtime.h>

// SAGEConv mean-aggregate + dual GEMV + sigmoid for MI355X (gfx950).
// in_feat [100000,64] f32, src/dst [1.6M] i32, W_self/W_neigh [64,64] f32, bias [64] f32.
// out = sigmoid(in_feat@W_self + (scatter-mean of in_feat over edges)@W_neigh + bias)

constexpr int NN = 100000;
constexpr int NE = 1600000;
constexpr int F  = 64;

// One wave (64 lanes) per edge; lane = feature index.
__global__ __launch_bounds__(256) void sage_scatter(
    const float* __restrict__ x, const int* __restrict__ src,
    const int* __restrict__ dst, float* __restrict__ agg,
    float* __restrict__ deg, int E)
{
    const int lane   = threadIdx.x & 63;
    const int wave   = (blockIdx.x * blockDim.x + threadIdx.x) >> 6;
    const int nwaves = (gridDim.x * blockDim.x) >> 6;
    for (int e = wave; e < E; e += nwaves) {
        const int s = src[e];
        const int d = dst[e];
        const float v = x[(size_t)s * F + lane];
        atomicAdd(&agg[(size_t)d * F + lane], v);
        if (lane == 0) atomicAdd(&deg[d], 1.0f);
    }
}

// One wave per node; lane = output column. W_self/W_neigh staged in LDS.
__global__ __launch_bounds__(256) void sage_node(
    const float* __restrict__ x, const float* __restrict__ agg,
    const float* __restrict__ deg, const float* __restrict__ Ws,
    const float* __restrict__ Wn, const float* __restrict__ bias,
    float* __restrict__ out, int N)
{
    __shared__ float sWs[F * F];
    __shared__ float sWn[F * F];
    __shared__ float sb[F];
    for (int i = threadIdx.x; i < F * F; i += blockDim.x) {
        sWs[i] = Ws[i];
        sWn[i] = Wn[i];
    }
    if (threadIdx.x < F) sb[threadIdx.x] = bias[threadIdx.x];
    __syncthreads();

    const int lane   = threadIdx.x & 63;
    const int wave   = (blockIdx.x * blockDim.x + threadIdx.x) >> 6;
    const int nwaves = (gridDim.x * blockDim.x) >> 6;
    for (int v = wave; v < N; v += nwaves) {
        const float xk = x[(size_t)v * F + lane];     // lane holds x[v][lane]
        const float dg = deg[v];                      // uniform broadcast
        const float hk = agg[(size_t)v * F + lane] / fmaxf(dg, 1.0f);
        float acc = sb[lane];
#pragma unroll
        for (int k = 0; k < F; ++k) {
            const float xb = __shfl(xk, k);
            const float hb = __shfl(hk, k);
            acc = fmaf(xb, sWs[k * F + lane], acc);   // lanes hit consecutive addrs: 2-way = free
            acc = fmaf(hb, sWn[k * F + lane], acc);
        }
        out[(size_t)v * F + lane] = 1.0f / (1.0f + __expf(-acc));
    }
}

extern "C" void kernel_launch(void* const* d_in, const int* in_sizes, int n_in,
                              void* d_out, int out_size, void* d_ws, size_t ws_size,
                              hipStream_t stream) {
    const float* x    = (const float*)d_in[0];
    const int*   src  = (const int*)d_in[1];
    const int*   dst  = (const int*)d_in[2];
    const float* Ws   = (const float*)d_in[3];
    const float* Wn   = (const float*)d_in[4];
    const float* bias = (const float*)d_in[5];
    float* out = (float*)d_out;

    float* agg = (float*)d_ws;                 // [NN * F]
    float* deg = agg + (size_t)NN * F;         // [NN]

    const size_t zero_bytes = ((size_t)NN * F + (size_t)NN) * sizeof(float);
    hipMemsetAsync(d_ws, 0, zero_bytes, stream);

    sage_scatter<<<2048, 256, 0, stream>>>(x, src, dst, agg, deg, NE);
    sage_node<<<2048, 256, 0, stream>>>(x, agg, deg, Ws, Wn, bias, out, NN);
}

// Round 2
// 345.371 us; speedup vs baseline: 1.6669x; 1.6669x over previous
//
#include <hip/hip_runtime.h>

// SAGEConv mean-aggregate + dual GEMV + sigmoid, CSR-build-per-call (no f32 atomics).
// in_feat [100000,64] f32, src/dst [1.6M] i32, W_self/W_neigh [64,64] f32, bias [64] f32.

constexpr int NN   = 100000;
constexpr int NE   = 1600000;
constexpr int F    = 64;
constexpr int NBLK = (NN + 255) / 256;   // 391

// ---------- CSR build ----------

__global__ __launch_bounds__(256) void k_hist(const int* __restrict__ dst,
                                              int* __restrict__ degi) {
    int e = blockIdx.x * 256 + threadIdx.x;
    if (e < NE) atomicAdd(&degi[dst[e]], 1);
}

__device__ __forceinline__ int block_incl_scan(int val, int* tmp, int t, int bs) {
    tmp[t] = val;
    __syncthreads();
    int s = val;
    for (int o = 1; o < bs; o <<= 1) {
        int add = (t >= o) ? tmp[t - o] : 0;
        __syncthreads();
        s += add;
        tmp[t] = s;
        __syncthreads();
    }
    return s;
}

__global__ __launch_bounds__(256) void k_bsum(const int* __restrict__ degi,
                                              int* __restrict__ bsum) {
    __shared__ int tmp[256];
    int t = threadIdx.x, v = blockIdx.x * 256 + t;
    int val = (v < NN) ? degi[v] : 0;
    int s = block_incl_scan(val, tmp, t, 256);
    if (t == 255) bsum[blockIdx.x] = s;
}

__global__ __launch_bounds__(512) void k_scanb(const int* __restrict__ bsum,
                                               int* __restrict__ boff) {
    __shared__ int tmp[512];
    int t = threadIdx.x;
    int val = (t < NBLK) ? bsum[t] : 0;
    int s = block_incl_scan(val, tmp, t, 512);
    if (t < NBLK) boff[t] = s - val;            // exclusive across blocks
}

__global__ __launch_bounds__(256) void k_off(const int* __restrict__ degi,
                                             const int* __restrict__ boff,
                                             int* __restrict__ off) {
    __shared__ int tmp[256];
    int t = threadIdx.x, v = blockIdx.x * 256 + t;
    int val = (v < NN) ? degi[v] : 0;
    int s = block_incl_scan(val, tmp, t, 256);
    if (v < NN) off[v] = boff[blockIdx.x] + s - val;   // exclusive per node
}

__global__ __launch_bounds__(256) void k_sort(const int* __restrict__ src,
                                              const int* __restrict__ dst,
                                              const int* __restrict__ off,
                                              int* __restrict__ cursor,
                                              int* __restrict__ ssrc) {
    int e = blockIdx.x * 256 + threadIdx.x;
    if (e < NE) {
        int d   = dst[e];
        int pos = atomicAdd(&cursor[d], 1);
        ssrc[off[d] + pos] = src[e];
    }
}

// ---------- fused aggregate + dual GEMV + sigmoid ----------

__global__ __launch_bounds__(256) void sage_node_csr(
    const float* __restrict__ x, const int* __restrict__ off,
    const int* __restrict__ degi, const int* __restrict__ ssrc,
    const float* __restrict__ Ws, const float* __restrict__ Wn,
    const float* __restrict__ bias, float* __restrict__ out, int N)
{
    __shared__ float sWs[F * F];
    __shared__ float sWn[F * F];
    __shared__ float sb[F];
    for (int i = threadIdx.x; i < F * F; i += blockDim.x) {
        sWs[i] = Ws[i];
        sWn[i] = Wn[i];
    }
    if (threadIdx.x < F) sb[threadIdx.x] = bias[threadIdx.x];
    __syncthreads();

    const int lane   = threadIdx.x & 63;
    const int wave   = (blockIdx.x * blockDim.x + threadIdx.x) >> 6;
    const int nwaves = (gridDim.x * blockDim.x) >> 6;

    for (int v = wave; v < N; v += nwaves) {
        const int e0 = off[v];
        const int dg = degi[v];
        float acc = 0.0f;
        int e = 0;
        for (; e + 4 <= dg; e += 4) {           // 4 gathers in flight
            int s0 = ssrc[e0 + e + 0];
            int s1 = ssrc[e0 + e + 1];
            int s2 = ssrc[e0 + e + 2];
            int s3 = ssrc[e0 + e + 3];
            float a0 = x[(size_t)s0 * F + lane];
            float a1 = x[(size_t)s1 * F + lane];
            float a2 = x[(size_t)s2 * F + lane];
            float a3 = x[(size_t)s3 * F + lane];
            acc += (a0 + a1) + (a2 + a3);
        }
        for (; e < dg; ++e)
            acc += x[(size_t)ssrc[e0 + e] * F + lane];

        const float h  = acc / fmaxf((float)dg, 1.0f);
        const float xk = x[(size_t)v * F + lane];

        float o = sb[lane];
#pragma unroll
        for (int k = 0; k < F; ++k) {
            // broadcast via readlane (scalar regs, no LDS traffic)
            const float xb = __int_as_float(__builtin_amdgcn_readlane(__float_as_int(xk), k));
            const float hb = __int_as_float(__builtin_amdgcn_readlane(__float_as_int(h),  k));
            o = fmaf(xb, sWs[k * F + lane], o);
            o = fmaf(hb, sWn[k * F + lane], o);
        }
        out[(size_t)v * F + lane] = 1.0f / (1.0f + __expf(-o));
    }
}

extern "C" void kernel_launch(void* const* d_in, const int* in_sizes, int n_in,
                              void* d_out, int out_size, void* d_ws, size_t ws_size,
                              hipStream_t stream) {
    const float* x    = (const float*)d_in[0];
    const int*   src  = (const int*)d_in[1];
    const int*   dst  = (const int*)d_in[2];
    const float* Ws   = (const float*)d_in[3];
    const float* Wn   = (const float*)d_in[4];
    const float* bias = (const float*)d_in[5];
    float* out = (float*)d_out;

    // ws layout: [degi NN][cursor NN][off NN][bsum NBLK][boff NBLK][ssrc NE]
    int* degi   = (int*)d_ws;
    int* cursor = degi + NN;
    int* off    = cursor + NN;
    int* bsum   = off + NN;
    int* boff   = bsum + NBLK;
    int* ssrc   = boff + NBLK;

    hipMemsetAsync(d_ws, 0, (size_t)2 * NN * sizeof(int), stream);  // degi + cursor

    const int EB = (NE + 255) / 256;
    k_hist <<<EB,   256, 0, stream>>>(dst, degi);
    k_bsum <<<NBLK, 256, 0, stream>>>(degi, bsum);
    k_scanb<<<1,    512, 0, stream>>>(bsum, boff);
    k_off  <<<NBLK, 256, 0, stream>>>(degi, boff, off);
    k_sort <<<EB,   256, 0, stream>>>(src, dst, off, cursor, ssrc);

    sage_node_csr<<<2048, 256, 0, stream>>>(x, off, degi, ssrc, Ws, Wn, bias, out, NN);
}

// Round 3
// 334.844 us; speedup vs baseline: 1.7193x; 1.0314x over previous
//
#include <hip/hip_runtime.h>

// SAGEConv mean-agg + dual GEMV + sigmoid. CSR build per call, split agg/gemv.
// in_feat [100000,64] f32, src/dst [1.6M] i32, W_self/W_neigh [64,64] f32, bias [64] f32.

constexpr int NN   = 100000;
constexpr int NE   = 1600000;
constexpr int F    = 64;
constexpr int NBLK = (NN + 255) / 256;   // 391

// ---------- CSR build ----------

__global__ __launch_bounds__(256) void k_hist(const int* __restrict__ dst,
                                              int* __restrict__ degi) {
    int i = blockIdx.x * 256 + threadIdx.x;
    if (i < NE / 4) {
        int4 d = ((const int4*)dst)[i];
        atomicAdd(&degi[d.x], 1);
        atomicAdd(&degi[d.y], 1);
        atomicAdd(&degi[d.z], 1);
        atomicAdd(&degi[d.w], 1);
    }
}

__global__ __launch_bounds__(256) void k_bsum(const int* __restrict__ degi,
                                              int* __restrict__ bsum) {
    __shared__ int tmp[256];
    int t = threadIdx.x, v = blockIdx.x * 256 + t;
    tmp[t] = (v < NN) ? degi[v] : 0;
    __syncthreads();
    for (int o = 128; o; o >>= 1) {
        if (t < o) tmp[t] += tmp[t + o];
        __syncthreads();
    }
    if (t == 0) bsum[blockIdx.x] = tmp[0];
}

// off[v] = exclusive scan of degi; also duplicates into cursor for k_sort.
__global__ __launch_bounds__(256) void k_off(const int* __restrict__ degi,
                                             const int* __restrict__ bsum,
                                             int* __restrict__ off,
                                             int* __restrict__ cursor) {
    __shared__ int red[256];
    const int t = threadIdx.x, bid = blockIdx.x, v = bid * 256 + t;
    // prefix over earlier blocks
    int pre = 0;
    for (int j = t; j < bid; j += 256) pre += bsum[j];
    red[t] = pre;
    __syncthreads();
    for (int o = 128; o; o >>= 1) {
        if (t < o) red[t] += red[t + o];
        __syncthreads();
    }
    const int base = red[0];
    __syncthreads();
    // local inclusive scan (Hillis-Steele)
    int val = (v < NN) ? degi[v] : 0;
    red[t] = val;
    __syncthreads();
    int s = val;
    for (int o = 1; o < 256; o <<= 1) {
        int add = (t >= o) ? red[t - o] : 0;
        __syncthreads();
        s += add;
        red[t] = s;
        __syncthreads();
    }
    if (v < NN) {
        int ex = base + s - val;
        off[v]    = ex;
        cursor[v] = ex;
    }
}

__global__ __launch_bounds__(256) void k_sort(const int* __restrict__ src,
                                              const int* __restrict__ dst,
                                              int* __restrict__ cursor,
                                              int* __restrict__ ssrc) {
    int i = blockIdx.x * 256 + threadIdx.x;
    if (i < NE / 4) {
        int4 s = ((const int4*)src)[i];
        int4 d = ((const int4*)dst)[i];
        ssrc[atomicAdd(&cursor[d.x], 1)] = s.x;
        ssrc[atomicAdd(&cursor[d.y], 1)] = s.y;
        ssrc[atomicAdd(&cursor[d.z], 1)] = s.z;
        ssrc[atomicAdd(&cursor[d.w], 1)] = s.w;
    }
}

// ---------- aggregation: 16 threads per node, float4 per thread ----------

__global__ __launch_bounds__(256) void k_agg(
    const float* __restrict__ x, const int* __restrict__ off,
    const int* __restrict__ degi, const int* __restrict__ ssrc,
    float* __restrict__ h)
{
    const int idx = blockIdx.x * 256 + threadIdx.x;
    const int v = idx >> 4;
    if (v >= NN) return;
    const int c = (idx & 15) * 4;

    const int e0 = off[v];
    const int dg = degi[v];
    float4 acc = make_float4(0.f, 0.f, 0.f, 0.f);
    int e = 0;
    for (; e + 4 <= dg; e += 4) {
        int s0 = ssrc[e0 + e + 0];
        int s1 = ssrc[e0 + e + 1];
        int s2 = ssrc[e0 + e + 2];
        int s3 = ssrc[e0 + e + 3];
        float4 a = *(const float4*)&x[(size_t)s0 * F + c];
        float4 b = *(const float4*)&x[(size_t)s1 * F + c];
        float4 g = *(const float4*)&x[(size_t)s2 * F + c];
        float4 d = *(const float4*)&x[(size_t)s3 * F + c];
        acc.x += (a.x + b.x) + (g.x + d.x);
        acc.y += (a.y + b.y) + (g.y + d.y);
        acc.z += (a.z + b.z) + (g.z + d.z);
        acc.w += (a.w + b.w) + (g.w + d.w);
    }
    for (; e < dg; ++e) {
        float4 a = *(const float4*)&x[(size_t)ssrc[e0 + e] * F + c];
        acc.x += a.x; acc.y += a.y; acc.z += a.z; acc.w += a.w;
    }
    const float inv = 1.0f / fmaxf((float)dg, 1.0f);
    *(float4*)&h[(size_t)v * F + c] =
        make_float4(acc.x * inv, acc.y * inv, acc.z * inv, acc.w * inv);
}

// ---------- dual GEMV + bias + sigmoid (reads h from out, writes in place) ----------

__global__ __launch_bounds__(256) void k_gemv(
    const float* __restrict__ x, const float* __restrict__ hbuf,
    const float* __restrict__ Ws, const float* __restrict__ Wn,
    const float* __restrict__ bias, float* __restrict__ out, int N)
{
    __shared__ float sWs[F * F];
    __shared__ float sWn[F * F];
    __shared__ float sb[F];
    for (int i = threadIdx.x; i < F * F; i += blockDim.x) {
        sWs[i] = Ws[i];
        sWn[i] = Wn[i];
    }
    if (threadIdx.x < F) sb[threadIdx.x] = bias[threadIdx.x];
    __syncthreads();

    const int lane   = threadIdx.x & 63;
    const int wave   = (blockIdx.x * blockDim.x + threadIdx.x) >> 6;
    const int nwaves = (gridDim.x * blockDim.x) >> 6;

    for (int v = wave; v < N; v += nwaves) {
        const float xk = x[(size_t)v * F + lane];
        const float hk = hbuf[(size_t)v * F + lane];
        float o = sb[lane];
#pragma unroll
        for (int k = 0; k < F; ++k) {
            const float xb = __int_as_float(__builtin_amdgcn_readlane(__float_as_int(xk), k));
            const float hb = __int_as_float(__builtin_amdgcn_readlane(__float_as_int(hk), k));
            o = fmaf(xb, sWs[k * F + lane], o);
            o = fmaf(hb, sWn[k * F + lane], o);
        }
        out[(size_t)v * F + lane] = 1.0f / (1.0f + __expf(-o));
    }
}

extern "C" void kernel_launch(void* const* d_in, const int* in_sizes, int n_in,
                              void* d_out, int out_size, void* d_ws, size_t ws_size,
                              hipStream_t stream) {
    const float* x    = (const float*)d_in[0];
    const int*   src  = (const int*)d_in[1];
    const int*   dst  = (const int*)d_in[2];
    const float* Ws   = (const float*)d_in[3];
    const float* Wn   = (const float*)d_in[4];
    const float* bias = (const float*)d_in[5];
    float* out = (float*)d_out;

    // ws: [degi NN][off NN][cursor NN][bsum NBLK][ssrc NE]
    int* degi   = (int*)d_ws;
    int* off    = degi + NN;
    int* cursor = off + NN;
    int* bsum   = cursor + NN;
    int* ssrc   = bsum + NBLK;

    hipMemsetAsync(degi, 0, (size_t)NN * sizeof(int), stream);

    const int EB4 = (NE / 4 + 255) / 256;
    k_hist<<<EB4,  256, 0, stream>>>(dst, degi);
    k_bsum<<<NBLK, 256, 0, stream>>>(degi, bsum);
    k_off <<<NBLK, 256, 0, stream>>>(degi, bsum, off, cursor);
    k_sort<<<EB4,  256, 0, stream>>>(src, dst, cursor, ssrc);

    // h staged in d_out, then gemv overwrites in place (per-wave read-before-write)
    const int AB = (NN * 16 + 255) / 256;   // 6250
    k_agg <<<AB,   256, 0, stream>>>(x, off, degi, ssrc, out);
    k_gemv<<<2048, 256, 0, stream>>>(x, out, Ws, Wn, bias, out, NN);
}